// Round 7
// baseline (1051.103 us; speedup 1.0000x reference)
//
#include <hip/hip_runtime.h>
#include <hip/hip_bf16.h>

#define EMB   256
#define KSORT 30
#define BATCH 48
#define NGPI  11
#define GG    528
#define NPG   192
#define EPG   384
#define DCH   769
#define GC    528                // graphs (single chunk)
#define MC    (GC*NPG)           // 101376 nodes
#define EC    (GC*EPG)           // 202752 edges
#define FQ    44                 // dense1 feature splits
#define FCH   (2816/FQ)          // 64 features per split
#define KB5   5                  // conv5 k-rows per block

__device__ __forceinline__ int clampi(int v, int lo, int hi) {
  return v < lo ? lo : (v > hi ? hi : v);
}

// ------------- static device scratch (~360 MB BSS; NEVER as host-side args) -
__device__ __attribute__((aligned(16))) float g_c1[MC * EMB];
__device__ __attribute__((aligned(16))) float g_c2[MC * EMB];
__device__ __attribute__((aligned(16))) float g_c3[MC * EMB];
__device__ __attribute__((aligned(16))) float g_dis[MC];
__device__ __attribute__((aligned(16))) float g_x4[MC];
__device__ __attribute__((aligned(16))) float g_s4[MC];      // layer-4 GEMV out
__device__ __attribute__((aligned(16))) int   g_indptr[MC + 1];
__device__ __attribute__((aligned(16))) int   g_ssrc[EC];
__device__ __attribute__((aligned(16))) int   g_idx[GC * KSORT];
__device__ __attribute__((aligned(16))) float g_w5t[DCH * 128];
__device__ __attribute__((aligned(16))) float g_w6t[640 * 256];
__device__ __attribute__((aligned(16))) float g_y[GC * 128 * 30];
__device__ __attribute__((aligned(16))) float g_z[GG * 2816];
__device__ __attribute__((aligned(16))) float g_hp[NGPI * FQ * BATCH * 256];
__device__ __attribute__((aligned(16))) float g_h[BATCH * 256];

__device__ __forceinline__ float* selbuf(int s) {
  return s == 0 ? g_c1 : (s == 1 ? g_c2 : g_c3);
}

// -------- graph-local CSR build + degree norm (all 528 graphs) --------------
__global__ __launch_bounds__(192) void build_csr_k(const int* __restrict__ src,
    const int* __restrict__ dst, int g0) {
  __shared__ int cnt[NPG];
  __shared__ int offs[NPG];
  int g = blockIdx.x, t = threadIdx.x;
  int gg = g0 + g;
  cnt[t] = 0;
  __syncthreads();
  int ebase = gg * EPG, gnb = gg * NPG, lnb = g * NPG;
  for (int e = t; e < EPG; e += 192) {
    int dl = clampi(dst[ebase + e] - gnb, 0, NPG - 1);
    atomicAdd(&cnt[dl], 1);
  }
  __syncthreads();
  if (t == 0) {
    int run = g * EPG;
    for (int i = 0; i < NPG; i++) { offs[i] = run; run += cnt[i]; }
  }
  __syncthreads();
  g_indptr[lnb + t] = offs[t];
  g_dis[lnb + t] = 1.0f / sqrtf(1.0f + (float)cnt[t]);
  if (g == 0 && t == 0) g_indptr[MC] = EC;
  __syncthreads();
  for (int e = t; e < EPG; e += 192) {
    int ee = ebase + e;
    int dl = clampi(dst[ee] - gnb, 0, NPG - 1);
    int pos = clampi(atomicAdd(&offs[dl], 1), 0, EC - 1);
    g_ssrc[pos] = clampi(src[ee] - gnb, 0, NPG - 1) + lnb;
  }
}

// ---- FUSED GCN layer: per-graph GEMM + aggregation + bias + tanh -----------
// grid (4 col-blocks, 528 graphs), 256 threads, 12x4 micro-tile (48 acc).
// Block owns ALL 192 rows x 64 cols of one graph -> aggregation (graph-local
// edges, column-independent) runs in-block from LDS; the g_tb round-trip
// (104MB write + ~200MB gather re-read per layer) is deleted.
// LDS aliased: k-loop uses As[16][200] (broadcast-friendly A slices, 4
// distinct addrs/wave-read); after the last barrier the same buffer holds
// H[192][68]. 52.2KB -> 3 blocks/CU. B read directly from W via L1
// (256B/wave/kk, ~17% of L1). A re-read 4x but L3-resident (104MB < 256MB).
// Per-element math order (k ascending, CSR edge order, bias, tanh) is
// IDENTICAL to the old gemm_k+agg_k pair -> bit-stable output.
template<bool AX>
__global__ __launch_bounds__(256) void gcn_k(const float* __restrict__ Ax,
    int asel, int osel, const float* __restrict__ W,
    const float* __restrict__ bias, int Kd) {
  __shared__ float lds[13056];           // max(As 3200, H 13056) floats
  const int cb = blockIdx.x, g = blockIdx.y;
  const int t = threadIdx.x;
  const int tx = t & 15, ty = t >> 4;
  const int n0 = cb * 64;
  const int base = g * NPG;
  float acc[12][4];
#pragma unroll
  for (int i = 0; i < 12; i++)
#pragma unroll
    for (int j = 0; j < 4; j++) acc[i][j] = 0.f;
  const float* Ap = (AX ? Ax : selbuf(asel)) + (size_t)base * Kd;
  const float* Wp = W + n0 + tx * 4;
  const int nt = Kd >> 4;
  float4 pf0, pf1, pf2, pf3;
  if (t < NPG) {
    const float* ap = Ap + (size_t)t * Kd;
    pf0 = *(const float4*)(ap + 0);
    pf1 = *(const float4*)(ap + 4);
    pf2 = *(const float4*)(ap + 8);
    pf3 = *(const float4*)(ap + 12);
  }
  for (int it = 0; it < nt; ++it) {
    if (t < NPG) {
      lds[ 0 * 200 + t] = pf0.x; lds[ 1 * 200 + t] = pf0.y;
      lds[ 2 * 200 + t] = pf0.z; lds[ 3 * 200 + t] = pf0.w;
      lds[ 4 * 200 + t] = pf1.x; lds[ 5 * 200 + t] = pf1.y;
      lds[ 6 * 200 + t] = pf1.z; lds[ 7 * 200 + t] = pf1.w;
      lds[ 8 * 200 + t] = pf2.x; lds[ 9 * 200 + t] = pf2.y;
      lds[10 * 200 + t] = pf2.z; lds[11 * 200 + t] = pf2.w;
      lds[12 * 200 + t] = pf3.x; lds[13 * 200 + t] = pf3.y;
      lds[14 * 200 + t] = pf3.z; lds[15 * 200 + t] = pf3.w;
    }
    __syncthreads();
    if (it + 1 < nt && t < NPG) {       // prefetch next k-slice into regs
      const float* ap = Ap + (size_t)t * Kd + (it + 1) * 16;
      pf0 = *(const float4*)(ap + 0);
      pf1 = *(const float4*)(ap + 4);
      pf2 = *(const float4*)(ap + 8);
      pf3 = *(const float4*)(ap + 12);
    }
    const float* Wk = Wp + (size_t)(it * 16) * EMB;
#pragma unroll
    for (int kk = 0; kk < 16; kk++) {
      float a[12], b[4];
      *(float4*)&a[0] = *(const float4*)&lds[kk * 200 + ty * 12];
      *(float4*)&a[4] = *(const float4*)&lds[kk * 200 + ty * 12 + 4];
      *(float4*)&a[8] = *(const float4*)&lds[kk * 200 + ty * 12 + 8];
      *(float4*)&b[0] = *(const float4*)(Wk + (size_t)kk * EMB);
#pragma unroll
      for (int i = 0; i < 12; i++)
#pragma unroll
        for (int j = 0; j < 4; j++) acc[i][j] += a[i] * b[j];
    }
    __syncthreads();
  }
  // ---- park H in LDS (As is dead past this barrier) ----
#pragma unroll
  for (int i = 0; i < 12; i++)
    *(float4*)&lds[(ty * 12 + i) * 68 + tx * 4] =
        make_float4(acc[i][0], acc[i][1], acc[i][2], acc[i][3]);
  __syncthreads();
  // ---- aggregation + bias + tanh, straight to c_out ----
  float4 bv = ((const float4*)bias)[cb * 16 + tx];
  float* outp = selbuf(osel);
#pragma unroll
  for (int i = 0; i < 12; i++) {
    int r = ty * 12 + i, n = base + r;
    float dn = g_dis[n];
    float sc = dn * dn;
    float ax = acc[i][0] * sc, ay = acc[i][1] * sc;
    float az = acc[i][2] * sc, aw = acc[i][3] * sc;
    int beg = g_indptr[n], end = g_indptr[n + 1];
    for (int j = beg; j < end; j++) {
      int ls = clampi(g_ssrc[j] - base, 0, NPG - 1);
      float c = g_dis[base + ls] * dn;
      const float4 v = *(const float4*)&lds[ls * 68 + tx * 4];
      ax += v.x * c; ay += v.y * c; az += v.z * c; aw += v.w * c;
    }
    float4 o;
    o.x = tanhf(ax + bv.x);
    o.y = tanhf(ay + bv.y);
    o.z = tanhf(az + bv.z);
    o.w = tanhf(aw + bv.w);
    *(float4*)(outp + (size_t)n * EMB + n0 + tx * 4) = o;
  }
}

// ---------------- layer-4 (EMB -> 1) GEMV: g_s4 = c3 . W4 -------------------
__global__ __launch_bounds__(256) void gemm4_k(const float* __restrict__ W4) {
  int n = blockIdx.x * 4 + (threadIdx.x >> 6);
  int lane = threadIdx.x & 63;
  float4 a = *(const float4*)(g_c3 + (size_t)n * EMB + lane * 4);
  float4 w = *(const float4*)(W4 + lane * 4);
  float s = a.x * w.x + a.y * w.y + a.z * w.z + a.w * w.w;
  for (int off = 32; off > 0; off >>= 1) s += __shfl_down(s, off, 64);
  if (lane == 0) g_s4[n] = s;
}

__global__ __launch_bounds__(256) void agg4_k(const float* __restrict__ b4) {
  int n = blockIdx.x * 256 + threadIdx.x;
  if (n >= MC) return;
  float dn = g_dis[n];
  float acc = g_s4[n] * dn * dn;
  int beg = g_indptr[n], end = g_indptr[n + 1];
  for (int j = beg; j < end; j++) {
    int s = g_ssrc[j];
    acc += g_s4[s] * g_dis[s] * dn;
  }
  g_x4[n] = tanhf(acc + b4[0]);
}

// ---------------- global_sort_pool: per-graph bitonic top-K -----------------
__global__ __launch_bounds__(256) void sortpool_k() {
  __shared__ float sv[256];
  __shared__ int si[256];
  int g = blockIdx.x, t = threadIdx.x;
  if (t < NPG) { sv[t] = g_x4[g * NPG + t]; si[t] = t; }
  else { sv[t] = -1e30f; si[t] = 1 << 20; }
  __syncthreads();
  for (int k = 2; k <= 256; k <<= 1) {
    for (int j = k >> 1; j > 0; j >>= 1) {
      int ixj = t ^ j;
      if (ixj > t) {
        float v1 = sv[t], v2 = sv[ixj];
        int i1 = si[t], i2 = si[ixj];
        bool before_t = (v1 > v2) || (v1 == v2 && i1 < i2);
        bool up = ((t & k) == 0);
        if (up ? !before_t : before_t) {
          sv[t] = v2; sv[ixj] = v1;
          si[t] = i2; si[ixj] = i1;
        }
      }
      __syncthreads();
    }
  }
  if (t < KSORT) g_idx[g * KSORT + t] = clampi(g * NPG + si[t], 0, MC - 1);
}

// ---------------- weight transposes -----------------------------------------
__global__ __launch_bounds__(256) void tw5_k(const float* __restrict__ w5) {
  int i = blockIdx.x * 256 + threadIdx.x;  // 128*769
  if (i >= 128 * DCH) return;
  int o = i / DCH, d = i % DCH;
  g_w5t[d * 128 + o] = w5[i];
}
__global__ __launch_bounds__(256) void tw6_k(const float* __restrict__ w6) {
  int i = blockIdx.x * 256 + threadIdx.x;  // 256*640
  if (i >= 256 * 640) return;
  int o = i / 640, ir = i % 640;
  g_w6t[ir * 256 + o] = w6[i];
}

// ------ conv5: gather-GEMM over top-K rows; 5 rows/block, grid (GC,6) -------
__global__ __launch_bounds__(128) void conv5_k(const float* __restrict__ bc5) {
  __shared__ float ar[KB5][772];
  int g = blockIdx.x, kb = blockIdx.y * KB5;
  int t = threadIdx.x;
  for (int kk = 0; kk < KB5; kk++) {
    int n = clampi(g_idx[g * KSORT + kb + kk], 0, MC - 1);
    const float* p1 = g_c1 + (size_t)n * EMB;
    const float* p2 = g_c2 + (size_t)n * EMB;
    const float* p3 = g_c3 + (size_t)n * EMB;
    for (int d = t; d < EMB; d += 128) {
      ar[kk][d] = p1[d];
      ar[kk][EMB + d] = p2[d];
      ar[kk][2 * EMB + d] = p3[d];
    }
    if (t == 0) ar[kk][768] = g_x4[n];
  }
  __syncthreads();
  float acc[KB5];
  float bias = bc5[t];
#pragma unroll
  for (int kk = 0; kk < KB5; kk++) acc[kk] = bias;
  const float* wbase = g_w5t + t;
  int d = 0;
  for (; d + 8 <= DCH; d += 8) {
    float w0 = wbase[(d + 0) * 128], w1 = wbase[(d + 1) * 128];
    float w2 = wbase[(d + 2) * 128], w3 = wbase[(d + 3) * 128];
    float w4 = wbase[(d + 4) * 128], w5 = wbase[(d + 5) * 128];
    float w6 = wbase[(d + 6) * 128], w7 = wbase[(d + 7) * 128];
#pragma unroll
    for (int kk = 0; kk < KB5; kk++) {
      float4 a0 = *(const float4*)&ar[kk][d];
      float4 a1 = *(const float4*)&ar[kk][d + 4];
      acc[kk] += a0.x * w0 + a0.y * w1 + a0.z * w2 + a0.w * w3 +
                 a1.x * w4 + a1.y * w5 + a1.z * w6 + a1.w * w7;
    }
  }
  for (; d < DCH; d++) {
    float wv = wbase[d * 128];
#pragma unroll
    for (int kk = 0; kk < KB5; kk++) acc[kk] += ar[kk][d] * wv;
  }
#pragma unroll
  for (int kk = 0; kk < KB5; kk++)
    g_y[(size_t)g * 3840 + t * KSORT + kb + kk] = fmaxf(acc[kk], 0.f);
}

// ------ conv6 (128ch, k=5) per graph; maxpool(2,2) fused into staging -------
__global__ __launch_bounds__(256) void conv6_k(const float* __restrict__ bc6,
                                               int g0) {
  __shared__ float s[128 * 16];
  int g = blockIdx.x, t = threadIdx.x;
  for (int i = t; i < 1920; i += 256) {
    int ch = i / 15, j = i % 15;
    const float* yp = g_y + (size_t)g * 3840 + ch * 30 + 2 * j;
    s[ch * 16 + j] = fmaxf(yp[0], yp[1]);
  }
  __syncthreads();
  float acc[11];
  float bias = bc6[t];
#pragma unroll
  for (int q = 0; q < 11; q++) acc[q] = bias;
  for (int i = 0; i < 128; i += 2) {
    float wA[5], wB[5];
#pragma unroll
    for (int r = 0; r < 5; r++) {
      wA[r] = g_w6t[(i * 5 + r) * 256 + t];
      wB[r] = g_w6t[((i + 1) * 5 + r) * 256 + t];
    }
    const float* sA = &s[i * 16];
    const float* sB = &s[(i + 1) * 16];
#pragma unroll
    for (int r = 0; r < 5; r++)
#pragma unroll
      for (int q = 0; q < 11; q++)
        acc[q] += sA[r + q] * wA[r] + sB[r + q] * wB[r];
  }
#pragma unroll
  for (int q = 0; q < 11; q++)
    g_z[(size_t)(g0 + g) * 2816 + t * 11 + q] = fmaxf(acc[q], 0.f);
}

// ------ dense1: grid (gi=11, ob=2, fq=44); prefetched weight octets ---------
__global__ __launch_bounds__(128) void dense1_k(const float* __restrict__ Wc1) {
  __shared__ float zs[BATCH][FCH];
  int gi = blockIdx.x;
  int obase = blockIdx.y * 128;
  int fq = blockIdx.z, f0 = fq * FCH;
  int t = threadIdx.x;
  for (int i = t; i < BATCH * FCH; i += 128) {
    int gl = i >> 6, f = i & 63;
    zs[gl][f] = g_z[(size_t)(gl * NGPI + gi) * 2816 + f0 + f];
  }
  __syncthreads();
  const float* wp = Wc1 + (size_t)gi * 2816 * 256 + (size_t)f0 * 256 + obase + t;
  float acc[BATCH];
#pragma unroll
  for (int gl = 0; gl < BATCH; gl++) acc[gl] = 0.f;
  float wc[8];
#pragma unroll
  for (int r = 0; r < 8; r++) wc[r] = wp[(size_t)r * 256];
  for (int f = 0; f < FCH; f += 8) {
    float wn[8];
    int fn = (f + 8 < FCH) ? f + 8 : f;
#pragma unroll
    for (int r = 0; r < 8; r++) wn[r] = wp[(size_t)(fn + r) * 256];
#pragma unroll
    for (int gl = 0; gl < BATCH; gl++) {
      float4 z0 = *(const float4*)&zs[gl][f];
      float4 z1 = *(const float4*)&zs[gl][f + 4];
      acc[gl] += z0.x * wc[0] + z0.y * wc[1] + z0.z * wc[2] + z0.w * wc[3] +
                 z1.x * wc[4] + z1.y * wc[5] + z1.z * wc[6] + z1.w * wc[7];
    }
#pragma unroll
    for (int r = 0; r < 8; r++) wc[r] = wn[r];
  }
  float* hp = g_hp + (size_t)(gi * FQ + fq) * (BATCH * 256);
#pragma unroll
  for (int gl = 0; gl < BATCH; gl++)
    hp[gl * 256 + obase + t] = acc[gl];
}

// ---------------- reduce partials: h = sum over 484 slices ------------------
__global__ __launch_bounds__(256) void reduce_k() {
  int j = blockIdx.x * 256 + threadIdx.x;  // 48*256
  if (j >= BATCH * 256) return;
  float s0 = 0.f, s1 = 0.f, s2 = 0.f, s3 = 0.f;
  const size_t STR = BATCH * 256;
  for (int p = 0; p < NGPI * FQ; p += 4) {
    s0 += g_hp[(size_t)(p + 0) * STR + j];
    s1 += g_hp[(size_t)(p + 1) * STR + j];
    s2 += g_hp[(size_t)(p + 2) * STR + j];
    s3 += g_hp[(size_t)(p + 3) * STR + j];
  }
  g_h[j] = (s0 + s1) + (s2 + s3);
}

// ---------------- final dense (fp32 out) ------------------------------------
__global__ __launch_bounds__(256) void dense2_k(const float* __restrict__ bc1,
    const float* __restrict__ Wc2, const float* __restrict__ bc2,
    float* __restrict__ out) {
  __shared__ float hs[BATCH * 256];
  int t = threadIdx.x;
  for (int i = t; i < BATCH * 256; i += 256) {
    int o = i & 255;
    hs[i] = fmaxf(g_h[i] + bc1[o], 0.f);
  }
  __syncthreads();
  for (int i = t; i < 480; i += 256) {
    int b = i / 10, c = i % 10;
    float acc = bc2[c];
    for (int k = 0; k < 256; k++) acc += hs[b * 256 + k] * Wc2[k * 10 + c];
    out[i] = acc;
  }
}

// ---------------- diag: stamp out with launch-error code --------------------
__global__ void diag_k(float* __restrict__ out, float v) {
  int i = blockIdx.x * 256 + threadIdx.x;
  if (i < 480) out[i] = v;
}

// ---------------- launch ----------------------------------------------------
extern "C" void kernel_launch(void* const* d_in, const int* in_sizes, int n_in,
                              void* d_out, int out_size, void* d_ws, size_t ws_size,
                              hipStream_t stream) {
  const float* x   = (const float*)d_in[0];
  const int*   src = (const int*)d_in[1];
  const int*   dst = (const int*)d_in[2];
  const float* W1  = (const float*)d_in[3];
  const float* b1  = (const float*)d_in[4];
  const float* W2  = (const float*)d_in[5];
  const float* b2  = (const float*)d_in[6];
  const float* W3  = (const float*)d_in[7];
  const float* b3  = (const float*)d_in[8];
  const float* W4  = (const float*)d_in[9];
  const float* b4  = (const float*)d_in[10];
  const float* w5  = (const float*)d_in[11];
  const float* bc5 = (const float*)d_in[12];
  const float* w6  = (const float*)d_in[13];
  const float* bc6 = (const float*)d_in[14];
  const float* Wc1 = (const float*)d_in[15];
  const float* bc1 = (const float*)d_in[16];
  const float* Wc2 = (const float*)d_in[17];
  const float* bc2 = (const float*)d_in[18];
  float* out = (float*)d_out;

  (void)hipGetLastError();
  int lcount = 0, fidx = -1;
  hipError_t ferr = hipSuccess;
  auto ck = [&]() {
    hipError_t e = hipGetLastError();
    if (e != hipSuccess && ferr == hipSuccess) { ferr = e; fidx = lcount; }
    lcount++;
  };

  tw5_k<<<(128 * DCH + 255) / 256, 256, 0, stream>>>(w5); ck();
  tw6_k<<<(256 * 640 + 255) / 256, 256, 0, stream>>>(w6); ck();

  dim3 gf(4, GC);
  build_csr_k<<<GC, 192, 0, stream>>>(src, dst, 0); ck();
  gcn_k<true><<<gf, 256, 0, stream>>>(x, 0, 0, W1, b1, 64); ck();
  gcn_k<false><<<gf, 256, 0, stream>>>(nullptr, 0, 1, W2, b2, EMB); ck();
  gcn_k<false><<<gf, 256, 0, stream>>>(nullptr, 1, 2, W3, b3, EMB); ck();
  gemm4_k<<<MC / 4, 256, 0, stream>>>(W4); ck();
  agg4_k<<<MC / 256, 256, 0, stream>>>(b4); ck();
  sortpool_k<<<GC, 256, 0, stream>>>(); ck();
  conv5_k<<<dim3(GC, 6), 128, 0, stream>>>(bc5); ck();
  conv6_k<<<GC, 256, 0, stream>>>(bc6, 0); ck();

  dense1_k<<<dim3(NGPI, 2, FQ), 128, 0, stream>>>(Wc1); ck();
  reduce_k<<<(BATCH * 256 + 255) / 256, 256, 0, stream>>>(); ck();
  dense2_k<<<1, 256, 0, stream>>>(bc1, Wc2, bc2, out); ck();

  if (ferr != hipSuccess) {
    int code = (int)ferr; if (code > 100) code = 100;
    float v = (fidx == 0) ? (1024.f + 8.f * code) : (2048.f + 16.f * code);
    diag_k<<<2, 256, 0, stream>>>(out, v);
  }
}

// Round 8
// 1017.598 us; speedup vs baseline: 1.0329x; 1.0329x over previous
//
#include <hip/hip_runtime.h>
#include <hip/hip_bf16.h>

#define EMB   256
#define KSORT 30
#define BATCH 48
#define NGPI  11
#define GG    528
#define NPG   192
#define EPG   384
#define DCH   769
#define GC    528                // graphs (single chunk)
#define MC    (GC*NPG)           // 101376 nodes
#define EC    (GC*EPG)           // 202752 edges
#define FQ    44                 // dense1 feature splits
#define FCH   (2816/FQ)          // 64 features per split

__device__ __forceinline__ int clampi(int v, int lo, int hi) {
  return v < lo ? lo : (v > hi ? hi : v);
}

// ------------- static device scratch (~360 MB BSS; NEVER as host-side args) -
__device__ __attribute__((aligned(16))) float g_c1[MC * EMB];
__device__ __attribute__((aligned(16))) float g_c2[MC * EMB];
__device__ __attribute__((aligned(16))) float g_c3[MC * EMB];
__device__ __attribute__((aligned(16))) float g_tb[MC * EMB];
__device__ __attribute__((aligned(16))) float g_dis[MC];
__device__ __attribute__((aligned(16))) float g_s4[MC];      // layer-4 GEMV out
__device__ __attribute__((aligned(16))) int   g_indptr[MC + 1];
__device__ __attribute__((aligned(16))) int   g_ssrc[EC];
__device__ __attribute__((aligned(16))) float g_w5t[DCH * 128];
__device__ __attribute__((aligned(16))) float g_w6t[640 * 256];
__device__ __attribute__((aligned(16))) float g_z[GG * 2816];
__device__ __attribute__((aligned(16))) float g_hp[NGPI * FQ * BATCH * 256];
__device__ __attribute__((aligned(16))) float g_h[BATCH * 256];

__device__ __forceinline__ float* selbuf(int s) {
  return s == 0 ? g_c1 : (s == 1 ? g_c2 : g_c3);
}

// -------- graph-local CSR build + degree norm (all 528 graphs) --------------
__global__ __launch_bounds__(192) void build_csr_k(const int* __restrict__ src,
    const int* __restrict__ dst, int g0) {
  __shared__ int cnt[NPG];
  __shared__ int offs[NPG];
  int g = blockIdx.x, t = threadIdx.x;
  int gg = g0 + g;
  cnt[t] = 0;
  __syncthreads();
  int ebase = gg * EPG, gnb = gg * NPG, lnb = g * NPG;
  for (int e = t; e < EPG; e += 192) {
    int dl = clampi(dst[ebase + e] - gnb, 0, NPG - 1);
    atomicAdd(&cnt[dl], 1);
  }
  __syncthreads();
  if (t == 0) {
    int run = g * EPG;
    for (int i = 0; i < NPG; i++) { offs[i] = run; run += cnt[i]; }
  }
  __syncthreads();
  g_indptr[lnb + t] = offs[t];
  g_dis[lnb + t] = 1.0f / sqrtf(1.0f + (float)cnt[t]);
  if (g == 0 && t == 0) g_indptr[MC] = EC;
  __syncthreads();
  for (int e = t; e < EPG; e += 192) {
    int ee = ebase + e;
    int dl = clampi(dst[ee] - gnb, 0, NPG - 1);
    int pos = clampi(atomicAdd(&offs[dl], 1), 0, EC - 1);
    g_ssrc[pos] = clampi(src[ee] - gnb, 0, NPG - 1) + lnb;
  }
}

// ---- fp32 tiled GEMM: g_tb[MC,256] = A[MC,Kd] @ W[Kd,256] ------------------
// R6-proven: 128x128 tile, 8x8 micro-tile, dual-source B (LDS quad + L1
// quad), padded-broadcast A layout. ~205us @ K=256, VGPR 100.
template<bool AX>
__global__ __launch_bounds__(256) void gemm_k(const float* __restrict__ Ax,
    int asel, const float* __restrict__ W, int Kd) {
  __shared__ float As[16 * 192];          // [kk][blk][12], 12.3 KB
  __shared__ float Bs[16][68];            // 16 k x 64 cols, 4.3 KB
  const int m0 = blockIdx.x * 128, n0 = blockIdx.y * 128;
  const int t = threadIdx.x;
  const int tx = t & 15, ty = t >> 4;
  const int arow = t >> 1, acol = (t & 1) * 8;
  const int awr = (arow >> 3) * 12 + (arow & 7);
  const int brow = t >> 4, bcol = tx * 4;
  float acc[8][8];
#pragma unroll
  for (int i = 0; i < 8; i++)
#pragma unroll
    for (int j = 0; j < 8; j++) acc[i][j] = 0.f;
  const float* Ap = AX ? Ax : selbuf(asel);
  const float* arp = Ap + (size_t)(m0 + arow) * Kd + acol;
  const float* bsp = W + (size_t)brow * EMB + n0 + bcol;
  const float* Wg = W + n0 + 64 + tx * 4;
  const int nt = Kd >> 4;
  float4 pa0 = *(const float4*)(arp);
  float4 pa1 = *(const float4*)(arp + 4);
  float4 pb  = *(const float4*)(bsp);
  for (int it = 0; it < nt; ++it) {
    As[(acol + 0) * 192 + awr] = pa0.x;
    As[(acol + 1) * 192 + awr] = pa0.y;
    As[(acol + 2) * 192 + awr] = pa0.z;
    As[(acol + 3) * 192 + awr] = pa0.w;
    As[(acol + 4) * 192 + awr] = pa1.x;
    As[(acol + 5) * 192 + awr] = pa1.y;
    As[(acol + 6) * 192 + awr] = pa1.z;
    As[(acol + 7) * 192 + awr] = pa1.w;
    *(float4*)&Bs[brow][bcol] = pb;
    __syncthreads();
    if (it + 1 < nt) {
      const float* ap = arp + (it + 1) * 16;
      pa0 = *(const float4*)(ap);
      pa1 = *(const float4*)(ap + 4);
      pb  = *(const float4*)(bsp + (size_t)(it + 1) * 16 * EMB);
    }
    const float* Wk = Wg + (size_t)(it * 16) * EMB;
#pragma unroll
    for (int kk = 0; kk < 16; kk++) {
      float a[8], b[8];
      *(float4*)&a[0] = *(const float4*)&As[kk * 192 + ty * 12];
      *(float4*)&a[4] = *(const float4*)&As[kk * 192 + ty * 12 + 4];
      *(float4*)&b[0] = *(const float4*)&Bs[kk][bcol];
      *(float4*)&b[4] = *(const float4*)(Wk + kk * EMB);
#pragma unroll
      for (int i = 0; i < 8; i++)
#pragma unroll
        for (int j = 0; j < 8; j++) acc[i][j] += a[i] * b[j];
    }
    __syncthreads();
  }
#pragma unroll
  for (int i = 0; i < 8; i++) {
    float* cp = g_tb + (size_t)(m0 + ty * 8 + i) * EMB + n0 + tx * 4;
    *(float4*)cp = make_float4(acc[i][0], acc[i][1], acc[i][2], acc[i][3]);
    *(float4*)(cp + 64) = make_float4(acc[i][4], acc[i][5], acc[i][6], acc[i][7]);
  }
}

// ------- fused aggregation + self loop + bias + tanh ------------------------
// XCD-chunked block swizzle: blocks of one graph stay on one XCD so the
// neighbor-gather window (196KB/graph) is L2-resident per XCD instead of
// being re-fetched by all 8. Bijective: 25344 blocks = 8 * 3168.
// When W4 != nullptr also computes the layer-4 GEMV (bit-identical to the
// old gemm4_k: same per-lane float4 dot + same __shfl_down order).
__global__ __launch_bounds__(256) void agg_k(int osel,
    const float* __restrict__ bias, const float* __restrict__ W4) {
  int nb = (blockIdx.x & 7) * (MC / 4 / 8) + (blockIdx.x >> 3);
  int n = nb * 4 + (threadIdx.x >> 6);
  int lane = threadIdx.x & 63;
  float dn = g_dis[n];
  const float4* H4 = (const float4*)g_tb;
  float4 hv = H4[(size_t)n * 64 + lane];
  float sc = dn * dn;
  float ax = hv.x * sc, ay = hv.y * sc, az = hv.z * sc, aw = hv.w * sc;
  int beg = g_indptr[n], end = g_indptr[n + 1];
  for (int j = beg; j < end; j++) {
    int s = g_ssrc[j];
    float c = g_dis[s] * dn;
    float4 v = H4[(size_t)s * 64 + lane];
    ax += v.x * c; ay += v.y * c; az += v.z * c; aw += v.w * c;
  }
  float4 bv = ((const float4*)bias)[lane];
  float4 o;
  o.x = tanhf(ax + bv.x);
  o.y = tanhf(ay + bv.y);
  o.z = tanhf(az + bv.z);
  o.w = tanhf(aw + bv.w);
  ((float4*)selbuf(osel))[(size_t)n * 64 + lane] = o;
  if (W4) {
    float4 w = ((const float4*)W4)[lane];
    float s = o.x * w.x + o.y * w.y + o.z * w.z + o.w * w.w;
    for (int off = 32; off > 0; off >>= 1) s += __shfl_down(s, off, 64);
    if (lane == 0) g_s4[n] = s;
  }
}

// ---------------- weight transposes -----------------------------------------
__global__ __launch_bounds__(256) void tw5_k(const float* __restrict__ w5) {
  int i = blockIdx.x * 256 + threadIdx.x;  // 128*769
  if (i >= 128 * DCH) return;
  int o = i / DCH, d = i % DCH;
  g_w5t[d * 128 + o] = w5[i];
}
__global__ __launch_bounds__(256) void tw6_k(const float* __restrict__ w6) {
  int i = blockIdx.x * 256 + threadIdx.x;  // 256*640
  if (i >= 256 * 640) return;
  int o = i / 640, ir = i % 640;
  g_w6t[ir * 256 + o] = w6[i];
}

// ---- FUSED TAIL per graph: agg4 + sortpool + conv5 + maxpool + conv6 -------
// One block per graph, 256 threads. x4 scores, sort indices, conv5 output y,
// and the pooled sequence all live in LDS; g_x4/g_idx/g_y round-trips and 3
// launches are deleted. Every phase is a line-for-line port of the previous
// kernels (same edge order, same bitonic compare, same d-ascending conv
// loops) -> bit-stable output.
// LDS: x4[192] + sv[256] + y[128*32] + ar[5*772] (s[128*16] aliases ar)
//      = 8404 floats + si[256] ints = 34.6 KB -> 4 blocks/CU.
__global__ __launch_bounds__(256) void tail_k(const float* __restrict__ b4,
    const float* __restrict__ bc5, const float* __restrict__ bc6) {
  __shared__ float fs[8404];
  __shared__ int si[256];
  const int X4 = 0, SV = 192, Y = 448, AR = 4544;
  const int g = blockIdx.x, t = threadIdx.x;
  const int gbase = g * NPG;
  // ---- phase 1: agg4 (x4 = tanh(agg(s4) + b4)), exact agg4_k port ----
  if (t < NPG) {
    int n = gbase + t;
    float dn = g_dis[n];
    float acc = g_s4[n] * dn * dn;
    int beg = g_indptr[n], end = g_indptr[n + 1];
    for (int j = beg; j < end; j++) {
      int s = g_ssrc[j];
      acc += g_s4[s] * g_dis[s] * dn;
    }
    fs[X4 + t] = tanhf(acc + b4[0]);
  }
  __syncthreads();
  // ---- phase 2: bitonic top-K (exact sortpool_k port) ----
  if (t < NPG) { fs[SV + t] = fs[X4 + t]; si[t] = t; }
  else { fs[SV + t] = -1e30f; si[t] = 1 << 20; }
  __syncthreads();
  for (int k = 2; k <= 256; k <<= 1) {
    for (int j = k >> 1; j > 0; j >>= 1) {
      int ixj = t ^ j;
      if (ixj > t) {
        float v1 = fs[SV + t], v2 = fs[SV + ixj];
        int i1 = si[t], i2 = si[ixj];
        bool before_t = (v1 > v2) || (v1 == v2 && i1 < i2);
        bool up = ((t & k) == 0);
        if (up ? !before_t : before_t) {
          fs[SV + t] = v2; fs[SV + ixj] = v1;
          si[t] = i2; si[ixj] = i1;
        }
      }
      __syncthreads();
    }
  }
  // ---- phase 3: conv5 (+ReLU) into y[128][32], 6 kb-groups of 5 rows ----
  const int ch = t & 127, half = t >> 7;
  for (int kb = 0; kb < 6; kb++) {
    for (int kk = 0; kk < 5; kk++) {
      int nl = clampi(si[kb * 5 + kk], 0, NPG - 1);
      const float* p1 = g_c1 + (size_t)(gbase + nl) * EMB;
      const float* p2 = g_c2 + (size_t)(gbase + nl) * EMB;
      const float* p3 = g_c3 + (size_t)(gbase + nl) * EMB;
      fs[AR + kk * 772 + t] = p1[t];
      fs[AR + kk * 772 + 256 + t] = p2[t];
      fs[AR + kk * 772 + 512 + t] = p3[t];
      if (t == 0) fs[AR + kk * 772 + 768] = fs[X4 + nl];
    }
    __syncthreads();
    // half 0 -> kk {0,2,4}; half 1 -> kk {1,3}
    const int k0 = half, k1 = half + 2, k2 = half + 4;  // k2 valid iff half==0
    float bias = bc5[ch];
    float a0 = bias, a1 = bias, a2 = bias;
    const float* wbase = g_w5t + ch;
    const float* r0 = &fs[AR + k0 * 772];
    const float* r1 = &fs[AR + k1 * 772];
    const float* r2 = &fs[AR + (half ? 0 : k2) * 772];
    int d = 0;
    for (; d + 8 <= DCH; d += 8) {
      float w0 = wbase[(d + 0) * 128], w1 = wbase[(d + 1) * 128];
      float w2 = wbase[(d + 2) * 128], w3 = wbase[(d + 3) * 128];
      float w4 = wbase[(d + 4) * 128], w5 = wbase[(d + 5) * 128];
      float w6 = wbase[(d + 6) * 128], w7 = wbase[(d + 7) * 128];
      {
        float4 x0 = *(const float4*)&r0[d];
        float4 x1 = *(const float4*)&r0[d + 4];
        a0 += x0.x * w0 + x0.y * w1 + x0.z * w2 + x0.w * w3 +
              x1.x * w4 + x1.y * w5 + x1.z * w6 + x1.w * w7;
      }
      {
        float4 x0 = *(const float4*)&r1[d];
        float4 x1 = *(const float4*)&r1[d + 4];
        a1 += x0.x * w0 + x0.y * w1 + x0.z * w2 + x0.w * w3 +
              x1.x * w4 + x1.y * w5 + x1.z * w6 + x1.w * w7;
      }
      {
        float4 x0 = *(const float4*)&r2[d];
        float4 x1 = *(const float4*)&r2[d + 4];
        a2 += x0.x * w0 + x0.y * w1 + x0.z * w2 + x0.w * w3 +
              x1.x * w4 + x1.y * w5 + x1.z * w6 + x1.w * w7;
      }
    }
    for (; d < DCH; d++) {
      float wv = wbase[d * 128];
      a0 += r0[d] * wv; a1 += r1[d] * wv; a2 += r2[d] * wv;
    }
    fs[Y + ch * 32 + kb * 5 + k0] = fmaxf(a0, 0.f);
    fs[Y + ch * 32 + kb * 5 + k1] = fmaxf(a1, 0.f);
    if (!half) fs[Y + ch * 32 + kb * 5 + k2] = fmaxf(a2, 0.f);
    __syncthreads();
  }
  // ---- phase 4: maxpool(2,2) into s[128][16] (aliases ar, dead) ----
  for (int i = t; i < 128 * 15; i += 256) {
    int c = i / 15, j = i % 15;
    fs[AR + c * 16 + j] =
        fmaxf(fs[Y + c * 32 + 2 * j], fs[Y + c * 32 + 2 * j + 1]);
  }
  __syncthreads();
  // ---- phase 5: conv6 (+ReLU) -> g_z (exact conv6_k port) ----
  float acc[11];
  float bias6 = bc6[t];
#pragma unroll
  for (int q = 0; q < 11; q++) acc[q] = bias6;
  for (int i = 0; i < 128; i += 2) {
    float wA[5], wB[5];
#pragma unroll
    for (int r = 0; r < 5; r++) {
      wA[r] = g_w6t[(i * 5 + r) * 256 + t];
      wB[r] = g_w6t[((i + 1) * 5 + r) * 256 + t];
    }
    const float* sA = &fs[AR + i * 16];
    const float* sB = &fs[AR + (i + 1) * 16];
#pragma unroll
    for (int r = 0; r < 5; r++)
#pragma unroll
      for (int q = 0; q < 11; q++)
        acc[q] += sA[r + q] * wA[r] + sB[r + q] * wB[r];
  }
#pragma unroll
  for (int q = 0; q < 11; q++)
    g_z[(size_t)g * 2816 + t * 11 + q] = fmaxf(acc[q], 0.f);
}

// ------ dense1: grid (gi=11, ob=2, fq=44); prefetched weight octets ---------
__global__ __launch_bounds__(128) void dense1_k(const float* __restrict__ Wc1) {
  __shared__ float zs[BATCH][FCH];
  int gi = blockIdx.x;
  int obase = blockIdx.y * 128;
  int fq = blockIdx.z, f0 = fq * FCH;
  int t = threadIdx.x;
  for (int i = t; i < BATCH * FCH; i += 128) {
    int gl = i >> 6, f = i & 63;
    zs[gl][f] = g_z[(size_t)(gl * NGPI + gi) * 2816 + f0 + f];
  }
  __syncthreads();
  const float* wp = Wc1 + (size_t)gi * 2816 * 256 + (size_t)f0 * 256 + obase + t;
  float acc[BATCH];
#pragma unroll
  for (int gl = 0; gl < BATCH; gl++) acc[gl] = 0.f;
  float wc[8];
#pragma unroll
  for (int r = 0; r < 8; r++) wc[r] = wp[(size_t)r * 256];
  for (int f = 0; f < FCH; f += 8) {
    float wn[8];
    int fn = (f + 8 < FCH) ? f + 8 : f;
#pragma unroll
    for (int r = 0; r < 8; r++) wn[r] = wp[(size_t)(fn + r) * 256];
#pragma unroll
    for (int gl = 0; gl < BATCH; gl++) {
      float4 z0 = *(const float4*)&zs[gl][f];
      float4 z1 = *(const float4*)&zs[gl][f + 4];
      acc[gl] += z0.x * wc[0] + z0.y * wc[1] + z0.z * wc[2] + z0.w * wc[3] +
                 z1.x * wc[4] + z1.y * wc[5] + z1.z * wc[6] + z1.w * wc[7];
    }
#pragma unroll
    for (int r = 0; r < 8; r++) wc[r] = wn[r];
  }
  float* hp = g_hp + (size_t)(gi * FQ + fq) * (BATCH * 256);
#pragma unroll
  for (int gl = 0; gl < BATCH; gl++)
    hp[gl * 256 + obase + t] = acc[gl];
}

// ---------------- reduce partials: h = sum over 484 slices ------------------
__global__ __launch_bounds__(256) void reduce_k() {
  int j = blockIdx.x * 256 + threadIdx.x;  // 48*256
  if (j >= BATCH * 256) return;
  float s0 = 0.f, s1 = 0.f, s2 = 0.f, s3 = 0.f;
  const size_t STR = BATCH * 256;
  for (int p = 0; p < NGPI * FQ; p += 4) {
    s0 += g_hp[(size_t)(p + 0) * STR + j];
    s1 += g_hp[(size_t)(p + 1) * STR + j];
    s2 += g_hp[(size_t)(p + 2) * STR + j];
    s3 += g_hp[(size_t)(p + 3) * STR + j];
  }
  g_h[j] = (s0 + s1) + (s2 + s3);
}

// ---------------- final dense (fp32 out) ------------------------------------
__global__ __launch_bounds__(256) void dense2_k(const float* __restrict__ bc1,
    const float* __restrict__ Wc2, const float* __restrict__ bc2,
    float* __restrict__ out) {
  __shared__ float hs[BATCH * 256];
  int t = threadIdx.x;
  for (int i = t; i < BATCH * 256; i += 256) {
    int o = i & 255;
    hs[i] = fmaxf(g_h[i] + bc1[o], 0.f);
  }
  __syncthreads();
  for (int i = t; i < 480; i += 256) {
    int b = i / 10, c = i % 10;
    float acc = bc2[c];
    for (int k = 0; k < 256; k++) acc += hs[b * 256 + k] * Wc2[k * 10 + c];
    out[i] = acc;
  }
}

// ---------------- diag: stamp out with launch-error code --------------------
__global__ void diag_k(float* __restrict__ out, float v) {
  int i = blockIdx.x * 256 + threadIdx.x;
  if (i < 480) out[i] = v;
}

// ---------------- launch ----------------------------------------------------
extern "C" void kernel_launch(void* const* d_in, const int* in_sizes, int n_in,
                              void* d_out, int out_size, void* d_ws, size_t ws_size,
                              hipStream_t stream) {
  const float* x   = (const float*)d_in[0];
  const int*   src = (const int*)d_in[1];
  const int*   dst = (const int*)d_in[2];
  const float* W1  = (const float*)d_in[3];
  const float* b1  = (const float*)d_in[4];
  const float* W2  = (const float*)d_in[5];
  const float* b2  = (const float*)d_in[6];
  const float* W3  = (const float*)d_in[7];
  const float* b3  = (const float*)d_in[8];
  const float* W4  = (const float*)d_in[9];
  const float* b4  = (const float*)d_in[10];
  const float* w5  = (const float*)d_in[11];
  const float* bc5 = (const float*)d_in[12];
  const float* w6  = (const float*)d_in[13];
  const float* bc6 = (const float*)d_in[14];
  const float* Wc1 = (const float*)d_in[15];
  const float* bc1 = (const float*)d_in[16];
  const float* Wc2 = (const float*)d_in[17];
  const float* bc2 = (const float*)d_in[18];
  float* out = (float*)d_out;

  (void)hipGetLastError();
  int lcount = 0, fidx = -1;
  hipError_t ferr = hipSuccess;
  auto ck = [&]() {
    hipError_t e = hipGetLastError();
    if (e != hipSuccess && ferr == hipSuccess) { ferr = e; fidx = lcount; }
    lcount++;
  };

  tw5_k<<<(128 * DCH + 255) / 256, 256, 0, stream>>>(w5); ck();
  tw6_k<<<(256 * 640 + 255) / 256, 256, 0, stream>>>(w6); ck();

  dim3 gg(MC / 128, 2);
  build_csr_k<<<GC, 192, 0, stream>>>(src, dst, 0); ck();
  gemm_k<true><<<gg, 256, 0, stream>>>(x, 0, W1, 64); ck();
  agg_k<<<MC / 4, 256, 0, stream>>>(0, b1, nullptr); ck();
  gemm_k<false><<<gg, 256, 0, stream>>>(nullptr, 0, W2, EMB); ck();
  agg_k<<<MC / 4, 256, 0, stream>>>(1, b2, nullptr); ck();
  gemm_k<false><<<gg, 256, 0, stream>>>(nullptr, 1, W3, EMB); ck();
  agg_k<<<MC / 4, 256, 0, stream>>>(2, b3, W4); ck();
  tail_k<<<GC, 256, 0, stream>>>(b4, bc5, bc6); ck();

  dense1_k<<<dim3(NGPI, 2, FQ), 128, 0, stream>>>(Wc1); ck();
  reduce_k<<<(BATCH * 256 + 255) / 256, 256, 0, stream>>>(); ck();
  dense2_k<<<1, 256, 0, stream>>>(bc1, Wc2, bc2, out); ck();

  if (ferr != hipSuccess) {
    int code = (int)ferr; if (code > 100) code = 100;
    float v = (fidx == 0) ? (1024.f + 8.f * code) : (2048.f + 16.f * code);
    diag_k<<<2, 256, 0, stream>>>(out, v);
  }
}

// Round 9
// 937.982 us; speedup vs baseline: 1.1206x; 1.0849x over previous
//
#include <hip/hip_runtime.h>
#include <hip/hip_bf16.h>

#define EMB   256
#define KSORT 30
#define BATCH 48
#define NGPI  11
#define GG    528
#define NPG   192
#define EPG   384
#define DCH   769
#define GC    528                // graphs (single chunk)
#define MC    (GC*NPG)           // 101376 nodes
#define EC    (GC*EPG)           // 202752 edges
#define FQ    44                 // dense1 feature splits
#define FCH   (2816/FQ)          // 64 features per split
#define KB5   5                  // conv5 k-rows per block

__device__ __forceinline__ int clampi(int v, int lo, int hi) {
  return v < lo ? lo : (v > hi ? hi : v);
}

// ------------- static device scratch (~370 MB BSS; NEVER as host-side args) -
__device__ __attribute__((aligned(16))) float g_c1[MC * EMB];
__device__ __attribute__((aligned(16))) float g_c2[MC * EMB];
__device__ __attribute__((aligned(16))) float g_c3[MC * EMB];
__device__ __attribute__((aligned(16))) float g_tb[MC * EMB];
__device__ __attribute__((aligned(16))) float g_dis[MC];
__device__ __attribute__((aligned(16))) float g_s4[MC];      // layer-4 GEMV out
__device__ __attribute__((aligned(16))) float g_x4[MC];
__device__ __attribute__((aligned(16))) int   g_indptr[MC + 1];
__device__ __attribute__((aligned(16))) int   g_ssrc[EC];
__device__ __attribute__((aligned(16))) int   g_idx[GC * KSORT];
__device__ __attribute__((aligned(16))) float g_w5t[DCH * 128];
__device__ __attribute__((aligned(16))) float g_w6t[640 * 256];
__device__ __attribute__((aligned(16))) float g_y[GC * 128 * 30];
__device__ __attribute__((aligned(16))) float g_z[GG * 2816];
__device__ __attribute__((aligned(16))) float g_hp[NGPI * FQ * BATCH * 256];
__device__ __attribute__((aligned(16))) float g_h[BATCH * 256];

__device__ __forceinline__ float* selbuf(int s) {
  return s == 0 ? g_c1 : (s == 1 ? g_c2 : g_c3);
}

// -------- graph-local CSR build + degree norm (all 528 graphs) --------------
__global__ __launch_bounds__(192) void build_csr_k(const int* __restrict__ src,
    const int* __restrict__ dst, int g0) {
  __shared__ int cnt[NPG];
  __shared__ int offs[NPG];
  int g = blockIdx.x, t = threadIdx.x;
  int gg = g0 + g;
  cnt[t] = 0;
  __syncthreads();
  int ebase = gg * EPG, gnb = gg * NPG, lnb = g * NPG;
  for (int e = t; e < EPG; e += 192) {
    int dl = clampi(dst[ebase + e] - gnb, 0, NPG - 1);
    atomicAdd(&cnt[dl], 1);
  }
  __syncthreads();
  if (t == 0) {
    int run = g * EPG;
    for (int i = 0; i < NPG; i++) { offs[i] = run; run += cnt[i]; }
  }
  __syncthreads();
  g_indptr[lnb + t] = offs[t];
  g_dis[lnb + t] = 1.0f / sqrtf(1.0f + (float)cnt[t]);
  if (g == 0 && t == 0) g_indptr[MC] = EC;
  __syncthreads();
  for (int e = t; e < EPG; e += 192) {
    int ee = ebase + e;
    int dl = clampi(dst[ee] - gnb, 0, NPG - 1);
    int pos = clampi(atomicAdd(&offs[dl], 1), 0, EC - 1);
    g_ssrc[pos] = clampi(src[ee] - gnb, 0, NPG - 1) + lnb;
  }
}

// ---- fp32 tiled GEMM: g_tb[MC,256] = A[MC,Kd] @ W[Kd,256] ------------------
// R6-proven: 128x128 tile, 8x8 micro-tile, dual-source B (LDS quad + L1
// quad), padded-broadcast A layout. ~205us @ K=256, VGPR 100.
template<bool AX>
__global__ __launch_bounds__(256) void gemm_k(const float* __restrict__ Ax,
    int asel, const float* __restrict__ W, int Kd) {
  __shared__ float As[16 * 192];          // [kk][blk][12], 12.3 KB
  __shared__ float Bs[16][68];            // 16 k x 64 cols, 4.3 KB
  const int m0 = blockIdx.x * 128, n0 = blockIdx.y * 128;
  const int t = threadIdx.x;
  const int tx = t & 15, ty = t >> 4;
  const int arow = t >> 1, acol = (t & 1) * 8;
  const int awr = (arow >> 3) * 12 + (arow & 7);
  const int brow = t >> 4, bcol = tx * 4;
  float acc[8][8];
#pragma unroll
  for (int i = 0; i < 8; i++)
#pragma unroll
    for (int j = 0; j < 8; j++) acc[i][j] = 0.f;
  const float* Ap = AX ? Ax : selbuf(asel);
  const float* arp = Ap + (size_t)(m0 + arow) * Kd + acol;
  const float* bsp = W + (size_t)brow * EMB + n0 + bcol;
  const float* Wg = W + n0 + 64 + tx * 4;
  const int nt = Kd >> 4;
  float4 pa0 = *(const float4*)(arp);
  float4 pa1 = *(const float4*)(arp + 4);
  float4 pb  = *(const float4*)(bsp);
  for (int it = 0; it < nt; ++it) {
    As[(acol + 0) * 192 + awr] = pa0.x;
    As[(acol + 1) * 192 + awr] = pa0.y;
    As[(acol + 2) * 192 + awr] = pa0.z;
    As[(acol + 3) * 192 + awr] = pa0.w;
    As[(acol + 4) * 192 + awr] = pa1.x;
    As[(acol + 5) * 192 + awr] = pa1.y;
    As[(acol + 6) * 192 + awr] = pa1.z;
    As[(acol + 7) * 192 + awr] = pa1.w;
    *(float4*)&Bs[brow][bcol] = pb;
    __syncthreads();
    if (it + 1 < nt) {
      const float* ap = arp + (it + 1) * 16;
      pa0 = *(const float4*)(ap);
      pa1 = *(const float4*)(ap + 4);
      pb  = *(const float4*)(bsp + (size_t)(it + 1) * 16 * EMB);
    }
    const float* Wk = Wg + (size_t)(it * 16) * EMB;
#pragma unroll
    for (int kk = 0; kk < 16; kk++) {
      float a[8], b[8];
      *(float4*)&a[0] = *(const float4*)&As[kk * 192 + ty * 12];
      *(float4*)&a[4] = *(const float4*)&As[kk * 192 + ty * 12 + 4];
      *(float4*)&b[0] = *(const float4*)&Bs[kk][bcol];
      *(float4*)&b[4] = *(const float4*)(Wk + kk * EMB);
#pragma unroll
      for (int i = 0; i < 8; i++)
#pragma unroll
        for (int j = 0; j < 8; j++) acc[i][j] += a[i] * b[j];
    }
    __syncthreads();
  }
#pragma unroll
  for (int i = 0; i < 8; i++) {
    float* cp = g_tb + (size_t)(m0 + ty * 8 + i) * EMB + n0 + tx * 4;
    *(float4*)cp = make_float4(acc[i][0], acc[i][1], acc[i][2], acc[i][3]);
    *(float4*)(cp + 64) = make_float4(acc[i][4], acc[i][5], acc[i][6], acc[i][7]);
  }
}

// ------- fused aggregation + self loop + bias + tanh ------------------------
// XCD-chunked block swizzle (bijective: 25344 = 8*3168): blocks of one graph
// stay on one XCD so the neighbor-gather window (196KB/graph) is L2-resident
// per XCD instead of being re-fetched by all 8. R8 evidence: ~110us saved
// across the 3 agg dispatches.
// When W4 != nullptr also computes the layer-4 GEMV (bit-identical to the
// old gemm4_k: same per-lane float4 dot + same __shfl_down order).
__global__ __launch_bounds__(256) void agg_k(int osel,
    const float* __restrict__ bias, const float* __restrict__ W4) {
  int nb = (blockIdx.x & 7) * (MC / 4 / 8) + (blockIdx.x >> 3);
  int n = nb * 4 + (threadIdx.x >> 6);
  int lane = threadIdx.x & 63;
  float dn = g_dis[n];
  const float4* H4 = (const float4*)g_tb;
  float4 hv = H4[(size_t)n * 64 + lane];
  float sc = dn * dn;
  float ax = hv.x * sc, ay = hv.y * sc, az = hv.z * sc, aw = hv.w * sc;
  int beg = g_indptr[n], end = g_indptr[n + 1];
  for (int j = beg; j < end; j++) {
    int s = g_ssrc[j];
    float c = g_dis[s] * dn;
    float4 v = H4[(size_t)s * 64 + lane];
    ax += v.x * c; ay += v.y * c; az += v.z * c; aw += v.w * c;
  }
  float4 bv = ((const float4*)bias)[lane];
  float4 o;
  o.x = tanhf(ax + bv.x);
  o.y = tanhf(ay + bv.y);
  o.z = tanhf(az + bv.z);
  o.w = tanhf(aw + bv.w);
  ((float4*)selbuf(osel))[(size_t)n * 64 + lane] = o;
  if (W4) {
    float4 w = ((const float4*)W4)[lane];
    float s = o.x * w.x + o.y * w.y + o.z * w.z + o.w * w.w;
    for (int off = 32; off > 0; off >>= 1) s += __shfl_down(s, off, 64);
    if (lane == 0) g_s4[n] = s;
  }
}

// ---- tail1: per-graph agg4 + bitonic sortpool (exact ports, merged) --------
__global__ __launch_bounds__(256) void tail1_k(const float* __restrict__ b4) {
  __shared__ float x4v[NPG];
  __shared__ float sv[256];
  __shared__ int si[256];
  const int g = blockIdx.x, t = threadIdx.x;
  const int gbase = g * NPG;
  if (t < NPG) {
    int n = gbase + t;
    float dn = g_dis[n];
    float acc = g_s4[n] * dn * dn;
    int beg = g_indptr[n], end = g_indptr[n + 1];
    for (int j = beg; j < end; j++) {
      int s = g_ssrc[j];
      acc += g_s4[s] * g_dis[s] * dn;
    }
    float v = tanhf(acc + b4[0]);
    x4v[t] = v;
    g_x4[n] = v;                       // conv5 reads this
  }
  __syncthreads();
  if (t < NPG) { sv[t] = x4v[t]; si[t] = t; }
  else { sv[t] = -1e30f; si[t] = 1 << 20; }
  __syncthreads();
  for (int k = 2; k <= 256; k <<= 1) {
    for (int j = k >> 1; j > 0; j >>= 1) {
      int ixj = t ^ j;
      if (ixj > t) {
        float v1 = sv[t], v2 = sv[ixj];
        int i1 = si[t], i2 = si[ixj];
        bool before_t = (v1 > v2) || (v1 == v2 && i1 < i2);
        bool up = ((t & k) == 0);
        if (up ? !before_t : before_t) {
          sv[t] = v2; sv[ixj] = v1;
          si[t] = i2; si[ixj] = i1;
        }
      }
      __syncthreads();
    }
  }
  if (t < KSORT) g_idx[g * KSORT + t] = clampi(gbase + si[t], 0, MC - 1);
}

// ---------------- weight transposes -----------------------------------------
__global__ __launch_bounds__(256) void tw5_k(const float* __restrict__ w5) {
  int i = blockIdx.x * 256 + threadIdx.x;  // 128*769
  if (i >= 128 * DCH) return;
  int o = i / DCH, d = i % DCH;
  g_w5t[d * 128 + o] = w5[i];
}
__global__ __launch_bounds__(256) void tw6_k(const float* __restrict__ w6) {
  int i = blockIdx.x * 256 + threadIdx.x;  // 256*640
  if (i >= 256 * 640) return;
  int o = i / 640, ir = i % 640;
  g_w6t[ir * 256 + o] = w6[i];
}

// ------ conv5: gather-GEMM over top-K rows; 5 rows/block, grid (GC,6) -------
__global__ __launch_bounds__(128) void conv5_k(const float* __restrict__ bc5) {
  __shared__ float ar[KB5][772];
  int g = blockIdx.x, kb = blockIdx.y * KB5;
  int t = threadIdx.x;
  for (int kk = 0; kk < KB5; kk++) {
    int n = clampi(g_idx[g * KSORT + kb + kk], 0, MC - 1);
    const float* p1 = g_c1 + (size_t)n * EMB;
    const float* p2 = g_c2 + (size_t)n * EMB;
    const float* p3 = g_c3 + (size_t)n * EMB;
    for (int d = t; d < EMB; d += 128) {
      ar[kk][d] = p1[d];
      ar[kk][EMB + d] = p2[d];
      ar[kk][2 * EMB + d] = p3[d];
    }
    if (t == 0) ar[kk][768] = g_x4[n];
  }
  __syncthreads();
  float acc[KB5];
  float bias = bc5[t];
#pragma unroll
  for (int kk = 0; kk < KB5; kk++) acc[kk] = bias;
  const float* wbase = g_w5t + t;
  int d = 0;
  for (; d + 8 <= DCH; d += 8) {
    float w0 = wbase[(d + 0) * 128], w1 = wbase[(d + 1) * 128];
    float w2 = wbase[(d + 2) * 128], w3 = wbase[(d + 3) * 128];
    float w4 = wbase[(d + 4) * 128], w5 = wbase[(d + 5) * 128];
    float w6 = wbase[(d + 6) * 128], w7 = wbase[(d + 7) * 128];
#pragma unroll
    for (int kk = 0; kk < KB5; kk++) {
      float4 a0 = *(const float4*)&ar[kk][d];
      float4 a1 = *(const float4*)&ar[kk][d + 4];
      acc[kk] += a0.x * w0 + a0.y * w1 + a0.z * w2 + a0.w * w3 +
                 a1.x * w4 + a1.y * w5 + a1.z * w6 + a1.w * w7;
    }
  }
  for (; d < DCH; d++) {
    float wv = wbase[d * 128];
#pragma unroll
    for (int kk = 0; kk < KB5; kk++) acc[kk] += ar[kk][d] * wv;
  }
#pragma unroll
  for (int kk = 0; kk < KB5; kk++)
    g_y[(size_t)g * 3840 + t * KSORT + kb + kk] = fmaxf(acc[kk], 0.f);
}

// ------ conv6 (128ch, k=5) per graph; maxpool(2,2) fused into staging -------
__global__ __launch_bounds__(256) void conv6_k(const float* __restrict__ bc6,
                                               int g0) {
  __shared__ float s[128 * 16];
  int g = blockIdx.x, t = threadIdx.x;
  for (int i = t; i < 1920; i += 256) {
    int ch = i / 15, j = i % 15;
    const float* yp = g_y + (size_t)g * 3840 + ch * 30 + 2 * j;
    s[ch * 16 + j] = fmaxf(yp[0], yp[1]);
  }
  __syncthreads();
  float acc[11];
  float bias = bc6[t];
#pragma unroll
  for (int q = 0; q < 11; q++) acc[q] = bias;
  for (int i = 0; i < 128; i += 2) {
    float wA[5], wB[5];
#pragma unroll
    for (int r = 0; r < 5; r++) {
      wA[r] = g_w6t[(i * 5 + r) * 256 + t];
      wB[r] = g_w6t[((i + 1) * 5 + r) * 256 + t];
    }
    const float* sA = &s[i * 16];
    const float* sB = &s[(i + 1) * 16];
#pragma unroll
    for (int r = 0; r < 5; r++)
#pragma unroll
      for (int q = 0; q < 11; q++)
        acc[q] += sA[r + q] * wA[r] + sB[r + q] * wB[r];
  }
#pragma unroll
  for (int q = 0; q < 11; q++)
    g_z[(size_t)(g0 + g) * 2816 + t * 11 + q] = fmaxf(acc[q], 0.f);
}

// ------ dense1: grid (gi=11, ob=2, fq=44); prefetched weight octets ---------
__global__ __launch_bounds__(128) void dense1_k(const float* __restrict__ Wc1) {
  __shared__ float zs[BATCH][FCH];
  int gi = blockIdx.x;
  int obase = blockIdx.y * 128;
  int fq = blockIdx.z, f0 = fq * FCH;
  int t = threadIdx.x;
  for (int i = t; i < BATCH * FCH; i += 128) {
    int gl = i >> 6, f = i & 63;
    zs[gl][f] = g_z[(size_t)(gl * NGPI + gi) * 2816 + f0 + f];
  }
  __syncthreads();
  const float* wp = Wc1 + (size_t)gi * 2816 * 256 + (size_t)f0 * 256 + obase + t;
  float acc[BATCH];
#pragma unroll
  for (int gl = 0; gl < BATCH; gl++) acc[gl] = 0.f;
  float wc[8];
#pragma unroll
  for (int r = 0; r < 8; r++) wc[r] = wp[(size_t)r * 256];
  for (int f = 0; f < FCH; f += 8) {
    float wn[8];
    int fn = (f + 8 < FCH) ? f + 8 : f;
#pragma unroll
    for (int r = 0; r < 8; r++) wn[r] = wp[(size_t)(fn + r) * 256];
#pragma unroll
    for (int gl = 0; gl < BATCH; gl++) {
      float4 z0 = *(const float4*)&zs[gl][f];
      float4 z1 = *(const float4*)&zs[gl][f + 4];
      acc[gl] += z0.x * wc[0] + z0.y * wc[1] + z0.z * wc[2] + z0.w * wc[3] +
                 z1.x * wc[4] + z1.y * wc[5] + z1.z * wc[6] + z1.w * wc[7];
    }
#pragma unroll
    for (int r = 0; r < 8; r++) wc[r] = wn[r];
  }
  float* hp = g_hp + (size_t)(gi * FQ + fq) * (BATCH * 256);
#pragma unroll
  for (int gl = 0; gl < BATCH; gl++)
    hp[gl * 256 + obase + t] = acc[gl];
}

// ---------------- reduce partials: h = sum over 484 slices ------------------
__global__ __launch_bounds__(256) void reduce_k() {
  int j = blockIdx.x * 256 + threadIdx.x;  // 48*256
  if (j >= BATCH * 256) return;
  float s0 = 0.f, s1 = 0.f, s2 = 0.f, s3 = 0.f;
  const size_t STR = BATCH * 256;
  for (int p = 0; p < NGPI * FQ; p += 4) {
    s0 += g_hp[(size_t)(p + 0) * STR + j];
    s1 += g_hp[(size_t)(p + 1) * STR + j];
    s2 += g_hp[(size_t)(p + 2) * STR + j];
    s3 += g_hp[(size_t)(p + 3) * STR + j];
  }
  g_h[j] = (s0 + s1) + (s2 + s3);
}

// ---------------- final dense (fp32 out) ------------------------------------
__global__ __launch_bounds__(256) void dense2_k(const float* __restrict__ bc1,
    const float* __restrict__ Wc2, const float* __restrict__ bc2,
    float* __restrict__ out) {
  __shared__ float hs[BATCH * 256];
  int t = threadIdx.x;
  for (int i = t; i < BATCH * 256; i += 256) {
    int o = i & 255;
    hs[i] = fmaxf(g_h[i] + bc1[o], 0.f);
  }
  __syncthreads();
  for (int i = t; i < 480; i += 256) {
    int b = i / 10, c = i % 10;
    float acc = bc2[c];
    for (int k = 0; k < 256; k++) acc += hs[b * 256 + k] * Wc2[k * 10 + c];
    out[i] = acc;
  }
}

// ---------------- diag: stamp out with launch-error code --------------------
__global__ void diag_k(float* __restrict__ out, float v) {
  int i = blockIdx.x * 256 + threadIdx.x;
  if (i < 480) out[i] = v;
}

// ---------------- launch ----------------------------------------------------
extern "C" void kernel_launch(void* const* d_in, const int* in_sizes, int n_in,
                              void* d_out, int out_size, void* d_ws, size_t ws_size,
                              hipStream_t stream) {
  const float* x   = (const float*)d_in[0];
  const int*   src = (const int*)d_in[1];
  const int*   dst = (const int*)d_in[2];
  const float* W1  = (const float*)d_in[3];
  const float* b1  = (const float*)d_in[4];
  const float* W2  = (const float*)d_in[5];
  const float* b2  = (const float*)d_in[6];
  const float* W3  = (const float*)d_in[7];
  const float* b3  = (const float*)d_in[8];
  const float* W4  = (const float*)d_in[9];
  const float* b4  = (const float*)d_in[10];
  const float* w5  = (const float*)d_in[11];
  const float* bc5 = (const float*)d_in[12];
  const float* w6  = (const float*)d_in[13];
  const float* bc6 = (const float*)d_in[14];
  const float* Wc1 = (const float*)d_in[15];
  const float* bc1 = (const float*)d_in[16];
  const float* Wc2 = (const float*)d_in[17];
  const float* bc2 = (const float*)d_in[18];
  float* out = (float*)d_out;

  (void)hipGetLastError();
  int lcount = 0, fidx = -1;
  hipError_t ferr = hipSuccess;
  auto ck = [&]() {
    hipError_t e = hipGetLastError();
    if (e != hipSuccess && ferr == hipSuccess) { ferr = e; fidx = lcount; }
    lcount++;
  };

  tw5_k<<<(128 * DCH + 255) / 256, 256, 0, stream>>>(w5); ck();
  tw6_k<<<(256 * 640 + 255) / 256, 256, 0, stream>>>(w6); ck();

  dim3 gg(MC / 128, 2);
  build_csr_k<<<GC, 192, 0, stream>>>(src, dst, 0); ck();
  gemm_k<true><<<gg, 256, 0, stream>>>(x, 0, W1, 64); ck();
  agg_k<<<MC / 4, 256, 0, stream>>>(0, b1, nullptr); ck();
  gemm_k<false><<<gg, 256, 0, stream>>>(nullptr, 0, W2, EMB); ck();
  agg_k<<<MC / 4, 256, 0, stream>>>(1, b2, nullptr); ck();
  gemm_k<false><<<gg, 256, 0, stream>>>(nullptr, 1, W3, EMB); ck();
  agg_k<<<MC / 4, 256, 0, stream>>>(2, b3, W4); ck();
  tail1_k<<<GC, 256, 0, stream>>>(b4); ck();
  conv5_k<<<dim3(GC, 6), 128, 0, stream>>>(bc5); ck();
  conv6_k<<<GC, 256, 0, stream>>>(bc6, 0); ck();

  dense1_k<<<dim3(NGPI, 2, FQ), 128, 0, stream>>>(Wc1); ck();
  reduce_k<<<(BATCH * 256 + 255) / 256, 256, 0, stream>>>(); ck();
  dense2_k<<<1, 256, 0, stream>>>(bc1, Wc2, bc2, out); ck();

  if (ferr != hipSuccess) {
    int code = (int)ferr; if (code > 100) code = 100;
    float v = (fidx == 0) ? (1024.f + 8.f * code) : (2048.f + 16.f * code);
    diag_k<<<2, 256, 0, stream>>>(out, v);
  }
}